// Round 2
// baseline (222.831 us; speedup 1.0000x reference)
//
#include <hip/hip_runtime.h>
#include <hip/hip_bf16.h>

typedef __attribute__((ext_vector_type(8))) short short8;
typedef __attribute__((ext_vector_type(4))) float floatx4;

#define D 128
#define BCAP 2048       // per-(bucket,sub) capacity; mean fill 383 -> hugely safe
#define CPAD 16         // bcnt padded to 16 ints = one line each (kills false sharing)

__device__ __forceinline__ unsigned short f2bf(float f) {
    unsigned u = __float_as_uint(f);
    u += 0x7FFFu + ((u >> 16) & 1u);   // round-to-nearest-even
    return (unsigned short)(u >> 16);
}
__device__ __forceinline__ float bf2f(unsigned short h) {
    return __uint_as_float(((unsigned)h) << 16);
}
__device__ __forceinline__ float bflo(unsigned p) { return __uint_as_float(p << 16); }
__device__ __forceinline__ float bfhi(unsigned p) { return __uint_as_float(p & 0xFFFF0000u); }

// Fused: blocks [0,eb4) bin edges by dst>>8 into 196 buckets x 8 sub-lists
// (line-padded counters; sub = blockIdx&7 ~ XCD) AND count per-node degree
// via fire-and-forget atomics (no return value -> no latency chain).
// Blocks [eb4,+128) do wconv.
__global__ __launch_bounds__(256) void bucket_wconv_kernel(const int* __restrict__ src,
                                                           const int* __restrict__ dst,
                                                           int* __restrict__ bcnt,
                                                           int* __restrict__ deg,
                                                           unsigned* __restrict__ bucket, int E,
                                                           const float* __restrict__ W1,
                                                           const float* __restrict__ W2,
                                                           unsigned short* __restrict__ whi1,
                                                           unsigned short* __restrict__ wlo1,
                                                           unsigned short* __restrict__ whi2,
                                                           unsigned short* __restrict__ wlo2,
                                                           int eb4) {
    int b = blockIdx.x;
    if (b >= eb4) {
        int gid = (b - eb4) * 256 + threadIdx.x;      // 0..32767
        int which = gid >> 14;
        int tid = gid & 16383;
        const float* W = which ? W2 : W1;
        unsigned short* whi = which ? whi2 : whi1;
        unsigned short* wlo = which ? wlo2 : wlo1;
        int j    = tid & 7;
        int col  = (tid >> 3) & 127;
        int quad = (tid >> 10) & 3;
        int kb   = tid >> 12;
        float wv = W[(kb * 32 + quad * 8 + j) * D + col];
        unsigned u = __float_as_uint(wv);
        unsigned short h = (unsigned short)(u >> 16);          // truncate for hi
        whi[tid] = h;
        wlo[tid] = f2bf(wv - bf2f(h));
        return;
    }
    int sub = b & 7;
    int t4 = (b * 256 + threadIdx.x) * 4;
    if (t4 + 3 < E) {
        int4 s = *reinterpret_cast<const int4*>(src + t4);
        int4 d = *reinterpret_cast<const int4*>(dst + t4);
        #pragma unroll
        for (int k = 0; k < 4; k++) {
            int dd = (k == 0) ? d.x : (k == 1) ? d.y : (k == 2) ? d.z : d.w;
            int ss = (k == 0) ? s.x : (k == 1) ? s.y : (k == 2) ? s.z : s.w;
            int slot = ((dd >> 8) << 3) | sub;
            atomicAdd(&deg[dd], 1);
            int pos = atomicAdd(&bcnt[slot * CPAD], 1);
            if (pos < BCAP)
                bucket[(size_t)slot * BCAP + pos] = ((unsigned)(dd & 255) << 16) | (unsigned)ss;
        }
    } else {
        for (int i = t4; i < E; i++) {
            int dd = dst[i], ss = src[i];
            int slot = ((dd >> 8) << 3) | sub;
            atomicAdd(&deg[dd], 1);
            int pos = atomicAdd(&bcnt[slot * CPAD], 1);
            if (pos < BCAP)
                bucket[(size_t)slot * BCAP + pos] = ((unsigned)(dd & 255) << 16) | (unsigned)ss;
        }
    }
}

__device__ __forceinline__ int block_excl_scan256(int v, int* lds, int tid) {
    int lane = tid & 63, wid = tid >> 6;
    int x = v;
    #pragma unroll
    for (int d = 1; d < 64; d <<= 1) {
        int y = __shfl_up(x, d, 64);
        if (lane >= d) x += y;
    }
    if (lane == 63) lds[wid] = x;
    __syncthreads();
    if (tid == 0) {
        int run = 0;
        #pragma unroll
        for (int i = 0; i < 4; i++) { int t2 = lds[i]; lds[i] = run; run += t2; }
    }
    __syncthreads();
    return lds[wid] + x - v;   // exclusive prefix within block
}

// Fused: blocks [0,nbuk) build the CSR. Degree comes straight from deg[]
// (counted by the binning kernel), so the old histogram pass (2nd bucket
// read + 600K LDS atomics) is gone: one scan, then a single scatter pass
// that emits PACKED 8-byte (src, coef) entries with coef = rsqrt(deg+1)
// computed here ONCE instead of gathered per-edge per-layer in the aggs.
// Blocks [nbuk, nbuk+gb) do the layer-1 GEMM — independent chains overlap.
__global__ __launch_bounds__(256) void build_gemm_kernel(const unsigned* __restrict__ bucket,
                                                         const int* __restrict__ bcnt,
                                                         const int* __restrict__ deg,
                                                         int* __restrict__ row_ptr,
                                                         float* __restrict__ dinv,
                                                         uint2* __restrict__ edata, int N, int E,
                                                         const float* __restrict__ A,
                                                         const unsigned short* __restrict__ whi,
                                                         const unsigned short* __restrict__ wlo,
                                                         unsigned short* __restrict__ C, int M,
                                                         int nbuk) {
    __shared__ int lds4[4];
    __shared__ int sbase[256];
    __shared__ int cur[256];
    int tid = threadIdx.x;
    int b = blockIdx.x;
    if (b < nbuk) {
        int tot = 0;
        if (tid < nbuk) {
            #pragma unroll
            for (int s = 0; s < 8; s++) tot += min(bcnt[(tid * 8 + s) * CPAD], BCAP);
        }
        int ex = block_excl_scan256(tot, lds4, tid);
        sbase[tid] = ex;
        __syncthreads();
        int base = sbase[b];
        int node = b * 256 + tid;
        int h = (node < N) ? deg[node] : 0;
        int off = block_excl_scan256(h, lds4, tid);
        cur[tid] = base + off;
        if (node < N) {
            row_ptr[node] = base + off;
            dinv[node] = rsqrtf((float)(h + 1));
        }
        if (b == 0 && tid == 0) row_ptr[N] = E;
        __syncthreads();
        for (int sub = 0; sub < 8; sub++) {
            int cnt = min(bcnt[(b * 8 + sub) * CPAD], BCAP);
            const unsigned* bp = bucket + (size_t)(b * 8 + sub) * BCAP;
            for (int i = tid; i < cnt; i += 256) {
                unsigned v = bp[i];
                int ss = (int)(v & 0xFFFFu);
                int p = atomicAdd(&cur[v >> 16], 1);
                float cs = rsqrtf((float)(deg[ss] + 1));
                uint2 ent; ent.x = (unsigned)ss; ent.y = __float_as_uint(cs);
                edata[p] = ent;
            }
        }
        return;
    }
    // ---- layer-1 GEMM: C[M,128](bf16) = A[M,128](fp32) @ W (hi/lo bf16 split)
    int lane = tid & 63, wid = tid >> 6;
    int quad = lane >> 4, l15 = lane & 15;
    int row0 = (b - nbuk) * 64;
    int n0 = wid * 32;

    short8 bhi[2][4], blo[2][4];
    #pragma unroll
    for (int t = 0; t < 2; t++)
        #pragma unroll
        for (int kb = 0; kb < 4; kb++) {
            size_t base = ((size_t)((kb * 4 + quad) * 128 + (n0 + t * 16 + l15))) * 8;
            bhi[t][kb] = *reinterpret_cast<const short8*>(whi + base);
            blo[t][kb] = *reinterpret_cast<const short8*>(wlo + base);
        }

    #pragma unroll
    for (int rg = 0; rg < 4; rg++) {
        int r0 = row0 + rg * 16;
        int ar = r0 + l15; if (ar > M - 1) ar = M - 1;
        short8 ahi[4], alo[4];
        #pragma unroll
        for (int kb = 0; kb < 4; kb++) {
            const float4* ap = reinterpret_cast<const float4*>(A + (size_t)ar * D + kb * 32 + quad * 8);
            float4 v0 = ap[0], v1 = ap[1];
            float vv[8] = {v0.x, v0.y, v0.z, v0.w, v1.x, v1.y, v1.z, v1.w};
            short8 vh, vl;
            #pragma unroll
            for (int j = 0; j < 8; j++) {
                unsigned u = __float_as_uint(vv[j]);
                unsigned short h = (unsigned short)(u >> 16);
                vh[j] = (short)h;
                vl[j] = (short)f2bf(vv[j] - bf2f(h));
            }
            ahi[kb] = vh;
            alo[kb] = vl;
        }
        floatx4 acc0 = {0.f, 0.f, 0.f, 0.f};
        floatx4 acc1 = {0.f, 0.f, 0.f, 0.f};
        #pragma unroll
        for (int kb = 0; kb < 4; kb++) {
            acc0 = __builtin_amdgcn_mfma_f32_16x16x32_bf16(ahi[kb], bhi[0][kb], acc0, 0, 0, 0);
            acc1 = __builtin_amdgcn_mfma_f32_16x16x32_bf16(ahi[kb], bhi[1][kb], acc1, 0, 0, 0);
            acc0 = __builtin_amdgcn_mfma_f32_16x16x32_bf16(ahi[kb], blo[0][kb], acc0, 0, 0, 0);
            acc1 = __builtin_amdgcn_mfma_f32_16x16x32_bf16(ahi[kb], blo[1][kb], acc1, 0, 0, 0);
            acc0 = __builtin_amdgcn_mfma_f32_16x16x32_bf16(alo[kb], bhi[0][kb], acc0, 0, 0, 0);
            acc1 = __builtin_amdgcn_mfma_f32_16x16x32_bf16(alo[kb], bhi[1][kb], acc1, 0, 0, 0);
        }
        #pragma unroll
        for (int r = 0; r < 4; r++) {
            int orow = r0 + quad * 4 + r;
            if (orow < M) {
                C[(size_t)orow * D + n0 + l15]      = f2bf(acc0[r]);
                C[(size_t)orow * D + n0 + 16 + l15] = f2bf(acc1[r]);
            }
        }
    }
}

// 4-edge FMA group kept in the exact expression form of the previous version
// (same association -> same rounding per group).
#define ACC4(c0, p0, c1, p1, c2, p2, c3, p3) \
    acc[0] += c0 * bflo(p0.x) + c1 * bflo(p1.x) + c2 * bflo(p2.x) + c3 * bflo(p3.x); \
    acc[1] += c0 * bfhi(p0.x) + c1 * bfhi(p1.x) + c2 * bfhi(p2.x) + c3 * bfhi(p3.x); \
    acc[2] += c0 * bflo(p0.y) + c1 * bflo(p1.y) + c2 * bflo(p2.y) + c3 * bflo(p3.y); \
    acc[3] += c0 * bfhi(p0.y) + c1 * bfhi(p1.y) + c2 * bfhi(p2.y) + c3 * bfhi(p3.y); \
    acc[4] += c0 * bflo(p0.z) + c1 * bflo(p1.z) + c2 * bflo(p2.z) + c3 * bflo(p3.z); \
    acc[5] += c0 * bfhi(p0.z) + c1 * bfhi(p1.z) + c2 * bfhi(p2.z) + c3 * bfhi(p3.z); \
    acc[6] += c0 * bflo(p0.w) + c1 * bflo(p1.w) + c2 * bflo(p2.w) + c3 * bflo(p3.w); \
    acc[7] += c0 * bfhi(p0.w) + c1 * bfhi(p1.w) + c2 * bfhi(p2.w) + c3 * bfhi(p3.w);

// Quarter-wave agg: 4 nodes/wave, 16 lanes/node, lane owns 8 features via one
// uint4 (16B) load per edge. Packed (src,coef) 8B entries: src and coefficient
// arrive in ONE uniform load (the old dependent dinv gather is gone). 8 edges
// in flight per iteration for 2x memory-level parallelism.
__device__ __forceinline__ void agg_qbody(const uint4* __restrict__ H4,
                                          const uint2* __restrict__ ed,
                                          const float* __restrict__ dinv,
                                          const int* __restrict__ row_ptr,
                                          const float* __restrict__ bias,
                                          int node, int fl, float* acc) {
    #pragma unroll
    for (int j = 0; j < 8; j++) acc[j] = 0.f;
    int beg = row_ptr[node], end = row_ptr[node + 1];
    int e = beg;
    for (; e + 8 <= end; e += 8) {
        uint2 q0 = ed[e],     q1 = ed[e + 1], q2 = ed[e + 2], q3 = ed[e + 3];
        uint2 q4 = ed[e + 4], q5 = ed[e + 5], q6 = ed[e + 6], q7 = ed[e + 7];
        uint4 p0 = H4[(size_t)q0.x * 16 + fl];
        uint4 p1 = H4[(size_t)q1.x * 16 + fl];
        uint4 p2 = H4[(size_t)q2.x * 16 + fl];
        uint4 p3 = H4[(size_t)q3.x * 16 + fl];
        uint4 p4 = H4[(size_t)q4.x * 16 + fl];
        uint4 p5 = H4[(size_t)q5.x * 16 + fl];
        uint4 p6 = H4[(size_t)q6.x * 16 + fl];
        uint4 p7 = H4[(size_t)q7.x * 16 + fl];
        float c0 = __uint_as_float(q0.y), c1 = __uint_as_float(q1.y);
        float c2 = __uint_as_float(q2.y), c3 = __uint_as_float(q3.y);
        float c4 = __uint_as_float(q4.y), c5 = __uint_as_float(q5.y);
        float c6 = __uint_as_float(q6.y), c7 = __uint_as_float(q7.y);
        ACC4(c0, p0, c1, p1, c2, p2, c3, p3);
        ACC4(c4, p4, c5, p5, c6, p6, c7, p7);
    }
    if (e + 4 <= end) {
        uint2 q0 = ed[e], q1 = ed[e + 1], q2 = ed[e + 2], q3 = ed[e + 3];
        uint4 p0 = H4[(size_t)q0.x * 16 + fl];
        uint4 p1 = H4[(size_t)q1.x * 16 + fl];
        uint4 p2 = H4[(size_t)q2.x * 16 + fl];
        uint4 p3 = H4[(size_t)q3.x * 16 + fl];
        float c0 = __uint_as_float(q0.y), c1 = __uint_as_float(q1.y);
        float c2 = __uint_as_float(q2.y), c3 = __uint_as_float(q3.y);
        ACC4(c0, p0, c1, p1, c2, p2, c3, p3);
        e += 4;
    }
    for (; e < end; e++) {
        uint2 q0 = ed[e];
        float c = __uint_as_float(q0.y);
        uint4 p0 = H4[(size_t)q0.x * 16 + fl];
        acc[0] += c * bflo(p0.x); acc[1] += c * bfhi(p0.x);
        acc[2] += c * bflo(p0.y); acc[3] += c * bfhi(p0.y);
        acc[4] += c * bflo(p0.z); acc[5] += c * bfhi(p0.z);
        acc[6] += c * bflo(p0.w); acc[7] += c * bfhi(p0.w);
    }
    float di = dinv[node];
    float dii = di * di;
    uint4 ps = H4[(size_t)node * 16 + fl];
    const float4* b4 = (const float4*)bias;
    float4 bb0 = b4[fl * 2], bb1 = b4[fl * 2 + 1];
    #pragma unroll
    for (int j = 0; j < 8; j++) acc[j] *= di;
    acc[0] += dii * bflo(ps.x) + bb0.x;
    acc[1] += dii * bfhi(ps.x) + bb0.y;
    acc[2] += dii * bflo(ps.y) + bb0.z;
    acc[3] += dii * bfhi(ps.y) + bb0.w;
    acc[4] += dii * bflo(ps.z) + bb1.x;
    acc[5] += dii * bfhi(ps.z) + bb1.y;
    acc[6] += dii * bflo(ps.w) + bb1.z;
    acc[7] += dii * bfhi(ps.w) + bb1.w;
}

// Fused layer-1 agg (+b1, ReLU) with row-local layer-2 GEMM on a 16x128 LDS
// tile (rows padded to 136 shorts: 16B-aligned, <=2-way bank aliasing).
__global__ __launch_bounds__(256) void agg_gemm2_kernel(const unsigned short* __restrict__ H,
                                                        const uint2* __restrict__ ed,
                                                        const float* __restrict__ dinv,
                                                        const int* __restrict__ row_ptr,
                                                        const float* __restrict__ bias,
                                                        const unsigned short* __restrict__ whi,
                                                        const unsigned short* __restrict__ wlo,
                                                        unsigned short* __restrict__ C, int N) {
    __shared__ unsigned short Asm[16 * 136];
    int tid = threadIdx.x;
    int node0 = blockIdx.x * 16;
    int r = tid >> 4;           // local row 0..15
    int fl = tid & 15;
    int node = node0 + r;
    float acc[8];
    if (node < N) {
        agg_qbody((const uint4*)H, ed, dinv, row_ptr, bias, node, fl, acc);
    } else {
        #pragma unroll
        for (int j = 0; j < 8; j++) acc[j] = 0.f;
    }
    short8 a;
    #pragma unroll
    for (int j = 0; j < 8; j++) a[j] = (short)f2bf(fmaxf(acc[j], 0.f));
    *reinterpret_cast<short8*>(&Asm[r * 136 + fl * 8]) = a;
    __syncthreads();

    // ---- layer-2 GEMM on the 16-row LDS tile
    int lane = tid & 63, wid = tid >> 6;
    int quad = lane >> 4, l15 = lane & 15;
    int n0 = wid * 32;
    floatx4 acc0 = {0.f, 0.f, 0.f, 0.f};
    floatx4 acc1 = {0.f, 0.f, 0.f, 0.f};
    #pragma unroll 1
    for (int kb = 0; kb < 4; kb++) {
        size_t wb = ((size_t)((kb * 4 + quad) * 128 + (n0 + l15))) * 8;
        short8 bh0 = *reinterpret_cast<const short8*>(whi + wb);
        short8 bh1 = *reinterpret_cast<const short8*>(whi + wb + 128);
        short8 bl0 = *reinterpret_cast<const short8*>(wlo + wb);
        short8 bl1 = *reinterpret_cast<const short8*>(wlo + wb + 128);
        short8 af = *reinterpret_cast<const short8*>(&Asm[l15 * 136 + kb * 32 + quad * 8]);
        acc0 = __builtin_amdgcn_mfma_f32_16x16x32_bf16(af, bh0, acc0, 0, 0, 0);
        acc1 = __builtin_amdgcn_mfma_f32_16x16x32_bf16(af, bh1, acc1, 0, 0, 0);
        acc0 = __builtin_amdgcn_mfma_f32_16x16x32_bf16(af, bl0, acc0, 0, 0, 0);
        acc1 = __builtin_amdgcn_mfma_f32_16x16x32_bf16(af, bl1, acc1, 0, 0, 0);
    }
    #pragma unroll
    for (int rr = 0; rr < 4; rr++) {
        int orow = node0 + quad * 4 + rr;
        if (orow < N) {
            C[(size_t)orow * D + n0 + l15]      = f2bf(acc0[rr]);
            C[(size_t)orow * D + n0 + 16 + l15] = f2bf(acc1[rr]);
        }
    }
}

// Layer-2 agg: fp32 float4 x2 output to d_out.
__global__ __launch_bounds__(256) void agg_f32out_kernel(const unsigned short* __restrict__ H,
                                                         const uint2* __restrict__ ed,
                                                         const float* __restrict__ dinv,
                                                         const int* __restrict__ row_ptr,
                                                         const float* __restrict__ bias,
                                                         float4* __restrict__ out, int N) {
    int node = blockIdx.x * 16 + (threadIdx.x >> 4);
    int fl = threadIdx.x & 15;
    if (node >= N) return;
    float acc[8];
    agg_qbody((const uint4*)H, ed, dinv, row_ptr, bias, node, fl, acc);
    float4 o0, o1;
    o0.x = acc[0]; o0.y = acc[1]; o0.z = acc[2]; o0.w = acc[3];
    o1.x = acc[4]; o1.y = acc[5]; o1.z = acc[6]; o1.w = acc[7];
    out[(size_t)node * 32 + fl * 2]     = o0;
    out[(size_t)node * 32 + fl * 2 + 1] = o1;
}

extern "C" void kernel_launch(void* const* d_in, const int* in_sizes, int n_in,
                              void* d_out, int out_size, void* d_ws, size_t ws_size,
                              hipStream_t stream) {
    const float* x  = (const float*)d_in[0];
    const int*   ei = (const int*)d_in[1];
    const float* W1 = (const float*)d_in[2];
    const float* b1 = (const float*)d_in[3];
    const float* W2 = (const float*)d_in[4];
    const float* b2 = (const float*)d_in[5];

    int N = in_sizes[0] / D;       // 50000 (pack requires N <= 65536)
    int E = in_sizes[1] / 2;       // 600000
    const int* src = ei;
    const int* dst = ei + E;

    int nbuk = (N + 255) / 256;    // 196 buckets

    char* ws = (char*)d_ws;
    int*      bcnt   = (int*)(ws + 0);                    // nbuk*8 ctrs, line-padded (100 KB)
    int*      deg    = (int*)(ws + 102400);               // N ints (200 KB)
    unsigned* bucket = (unsigned*)(ws + 307200);          // nbuk*8*BCAP*4 = 12.85 MB
    int*      row_ptr= (int*)(ws + 13152256);             // N+1 ints
    float*    dinv   = (float*)(ws + 13357056);           // N floats
    uint2*    edata  = (uint2*)(ws + 13561856);           // E x 8B (src, coef), dst-sorted
    unsigned short* whi1 = (unsigned short*)(ws + 18366464);
    unsigned short* wlo1 = (unsigned short*)(ws + 18399232);
    unsigned short* whi2 = (unsigned short*)(ws + 18432000);
    unsigned short* wlo2 = (unsigned short*)(ws + 18464768);
    unsigned short* hfeat = (unsigned short*)(ws + 18497536); // N*D bf16 (12.8 MB) : h1 = x@W1
    unsigned short* h2    = (unsigned short*)(ws + 31297536); // N*D bf16 (12.8 MB) : relu(agg1)@W2

    int eb4  = (E / 4 + 255) / 256;   // 4-edge-per-thread blocks (586)
    int gb   = (N + 63) / 64;         // gemm blocks (782)
    int ab16 = (N + 15) / 16;         // agg blocks (16 nodes/block)

    hipMemsetAsync(bcnt, 0, 307200, stream);   // bcnt + deg in one memset
    bucket_wconv_kernel<<<eb4 + 128, 256, 0, stream>>>(src, dst, bcnt, deg, bucket, E,
                                                       W1, W2, whi1, wlo1, whi2, wlo2, eb4);

    // CSR build (single pass, packed (src,coef) entries) + layer-1 GEMM fused
    build_gemm_kernel<<<nbuk + gb, 256, 0, stream>>>(bucket, bcnt, deg, row_ptr, dinv, edata,
                                                     N, E, x, whi1, wlo1, hfeat, N, nbuk);

    // layer 1 agg + b1 + relu fused with layer-2 GEMM -> h2 (bf16)
    agg_gemm2_kernel<<<ab16, 256, 0, stream>>>(hfeat, edata, dinv, row_ptr, b1,
                                               whi2, wlo2, h2, N);

    // layer 2 agg + b2 -> d_out (fp32)
    agg_f32out_kernel<<<ab16, 256, 0, stream>>>(h2, edata, dinv, row_ptr, b2,
                                                (float4*)d_out, N);
}

// Round 3
// 167.975 us; speedup vs baseline: 1.3266x; 1.3266x over previous
//
#include <hip/hip_runtime.h>
#include <hip/hip_bf16.h>

typedef __attribute__((ext_vector_type(8))) short short8;
typedef __attribute__((ext_vector_type(4))) float floatx4;

#define D 128
#define BCAP 2048       // per-(bucket,sub) capacity; mean fill 383 -> hugely safe
#define CPAD 16         // bcnt padded to 16 ints = one line each (kills false sharing)
#define NBIN 256        // binning blocks (1/CU); each owns ~E/256 edges
#define EPBMAX 2560     // LDS staging capacity per bin block (E <= 655360)

__device__ __forceinline__ unsigned short f2bf(float f) {
    unsigned u = __float_as_uint(f);
    u += 0x7FFFu + ((u >> 16) & 1u);   // round-to-nearest-even
    return (unsigned short)(u >> 16);
}
__device__ __forceinline__ float bf2f(unsigned short h) {
    return __uint_as_float(((unsigned)h) << 16);
}
__device__ __forceinline__ float bflo(unsigned p) { return __uint_as_float(p << 16); }
__device__ __forceinline__ float bfhi(unsigned p) { return __uint_as_float(p & 0xFFFF0000u); }

__device__ __forceinline__ int block_excl_scan256(int v, int* lds, int tid) {
    int lane = tid & 63, wid = tid >> 6;
    int x = v;
    #pragma unroll
    for (int d = 1; d < 64; d <<= 1) {
        int y = __shfl_up(x, d, 64);
        if (lane >= d) x += y;
    }
    if (lane == 63) lds[wid] = x;
    __syncthreads();
    if (tid == 0) {
        int run = 0;
        #pragma unroll
        for (int i = 0; i < 4; i++) { int t2 = lds[i]; lds[i] = run; run += t2; }
    }
    __syncthreads();
    return lds[wid] + x - v;   // exclusive prefix within block
}

// Fused: blocks [0,NBIN) bin edges by dst>>8 into 196 buckets x 8 sub-lists.
// Block-local: LDS histogram (LDS atomics, no global round-trip per edge),
// ONE global atomicAdd per (bucket,block) to reserve a range (issued by 196
// parallel threads -> single latency hop), LDS counting-sort by bucket, then
// coalesced run writes (~12 consecutive entries/bucket). Replaces the old
// per-edge global atomic + 64-way scattered 4B stores that made this kernel
// latency-bound at 9% HBM. Blocks [NBIN,+128) do wconv.
__global__ __launch_bounds__(256) void bucket_wconv_kernel(const int* __restrict__ src,
                                                           const int* __restrict__ dst,
                                                           int* __restrict__ bcnt,
                                                           unsigned* __restrict__ bucket, int E,
                                                           const float* __restrict__ W1,
                                                           const float* __restrict__ W2,
                                                           unsigned short* __restrict__ whi1,
                                                           unsigned short* __restrict__ wlo1,
                                                           unsigned short* __restrict__ whi2,
                                                           unsigned short* __restrict__ wlo2,
                                                           int nbuk) {
    int b = blockIdx.x;
    if (b >= NBIN) {
        int gid = (b - NBIN) * 256 + threadIdx.x;      // 0..32767
        int which = gid >> 14;
        int tid = gid & 16383;
        const float* W = which ? W2 : W1;
        unsigned short* whi = which ? whi2 : whi1;
        unsigned short* wlo = which ? wlo2 : wlo1;
        int j    = tid & 7;
        int col  = (tid >> 3) & 127;
        int quad = (tid >> 10) & 3;
        int kb   = tid >> 12;
        float wv = W[(kb * 32 + quad * 8 + j) * D + col];
        unsigned u = __float_as_uint(wv);
        unsigned short h = (unsigned short)(u >> 16);          // truncate for hi
        whi[tid] = h;
        wlo[tid] = f2bf(wv - bf2f(h));
        return;
    }
    __shared__ unsigned lent[EPBMAX];
    __shared__ unsigned sorted_e[EPBMAX];
    __shared__ int sdst[EPBMAX];
    __shared__ unsigned short loff[EPBMAX];
    __shared__ unsigned char lbkt[EPBMAX];
    __shared__ int hist[256];
    __shared__ int lstart[256];
    __shared__ int gbase[256];
    __shared__ int lds4[4];

    int tid = threadIdx.x;
    int sub = b & 7;
    int epb = (E + NBIN - 1) / NBIN;
    int beg = b * epb;
    int cnt = E - beg;
    if (cnt > epb) cnt = epb;
    if (cnt < 0) cnt = 0;

    hist[tid] = 0;
    __syncthreads();

    // phase 1: load edges (coalesced), stage entry + bucket + local offset
    for (int i = tid; i < cnt; i += 256) {
        int dd = dst[beg + i], ss = src[beg + i];
        int bk = dd >> 8;
        lent[i] = ((unsigned)(dd & 255) << 16) | (unsigned)ss;
        lbkt[i] = (unsigned char)bk;
        loff[i] = (unsigned short)atomicAdd(&hist[bk], 1);
    }
    __syncthreads();

    // phase 2: local exclusive scan + bulk global reservation (parallel)
    int h = hist[tid];
    int ex = block_excl_scan256(h, lds4, tid);
    lstart[tid] = ex;
    if (tid < nbuk && h > 0)
        gbase[tid] = atomicAdd(&bcnt[(tid * 8 + sub) * CPAD], h);
    __syncthreads();

    // phase 3: counting-sort into LDS (position-indexed global dest alongside)
    for (int i = tid; i < cnt; i += 256) {
        int bk = lbkt[i];
        int of = loff[i];
        int lp = lstart[bk] + of;
        int gp = gbase[bk] + of;
        sorted_e[lp] = lent[i];
        sdst[lp] = (gp < BCAP) ? ((bk * 8 + sub) * BCAP + gp) : -1;
    }
    __syncthreads();

    // phase 4: coalesced run writes (consecutive lanes -> consecutive dests)
    for (int i = tid; i < cnt; i += 256) {
        int dsti = sdst[i];
        if (dsti >= 0) bucket[dsti] = sorted_e[i];
    }
}

// Fused: blocks [0,nbuk) build the CSR (redundant all-bucket base scan, LDS
// histogram -> row_ptr/dinv, L2-local scatter of sorted src); blocks
// [nbuk, nbuk+gb) do the layer-1 GEMM (needs only wconv output) — independent
// chains overlap: build's LDS-atomic latency hides under GEMM compute.
__global__ __launch_bounds__(256) void build_gemm_kernel(const unsigned* __restrict__ bucket,
                                                         const int* __restrict__ bcnt,
                                                         int* __restrict__ row_ptr,
                                                         float* __restrict__ dinv,
                                                         int* __restrict__ esrc, int N, int E,
                                                         const float* __restrict__ A,
                                                         const unsigned short* __restrict__ whi,
                                                         const unsigned short* __restrict__ wlo,
                                                         unsigned short* __restrict__ C, int M,
                                                         int nbuk) {
    __shared__ int lds4[4];
    __shared__ int sbase[256];
    __shared__ int hist[256];
    __shared__ int cur[256];
    int tid = threadIdx.x;
    int b = blockIdx.x;
    if (b < nbuk) {
        int tot = 0;
        if (tid < nbuk) {
            #pragma unroll
            for (int s = 0; s < 8; s++) tot += min(bcnt[(tid * 8 + s) * CPAD], BCAP);
        }
        int ex = block_excl_scan256(tot, lds4, tid);
        sbase[tid] = ex;
        hist[tid] = 0;
        __syncthreads();
        int base = sbase[b];
        for (int sub = 0; sub < 8; sub++) {
            int cnt = min(bcnt[(b * 8 + sub) * CPAD], BCAP);
            const unsigned* bp = bucket + (size_t)(b * 8 + sub) * BCAP;
            for (int i = tid; i < cnt; i += 256)
                atomicAdd(&hist[bp[i] >> 16], 1);
        }
        __syncthreads();
        int h = hist[tid];
        int off = block_excl_scan256(h, lds4, tid);
        cur[tid] = base + off;
        int node = b * 256 + tid;
        if (node < N) {
            row_ptr[node] = base + off;
            dinv[node] = rsqrtf((float)(h + 1));
        }
        if (b == 0 && tid == 0) row_ptr[N] = E;
        __syncthreads();
        for (int sub = 0; sub < 8; sub++) {
            int cnt = min(bcnt[(b * 8 + sub) * CPAD], BCAP);
            const unsigned* bp = bucket + (size_t)(b * 8 + sub) * BCAP;
            for (int i = tid; i < cnt; i += 256) {
                unsigned v = bp[i];
                int p = atomicAdd(&cur[v >> 16], 1);
                esrc[p] = (int)(v & 0xFFFFu);
            }
        }
        return;
    }
    // ---- layer-1 GEMM: C[M,128](bf16) = A[M,128](fp32) @ W (hi/lo bf16 split)
    int lane = tid & 63, wid = tid >> 6;
    int quad = lane >> 4, l15 = lane & 15;
    int row0 = (b - nbuk) * 64;
    int n0 = wid * 32;

    short8 bhi[2][4], blo[2][4];
    #pragma unroll
    for (int t = 0; t < 2; t++)
        #pragma unroll
        for (int kb = 0; kb < 4; kb++) {
            size_t base = ((size_t)((kb * 4 + quad) * 128 + (n0 + t * 16 + l15))) * 8;
            bhi[t][kb] = *reinterpret_cast<const short8*>(whi + base);
            blo[t][kb] = *reinterpret_cast<const short8*>(wlo + base);
        }

    #pragma unroll
    for (int rg = 0; rg < 4; rg++) {
        int r0 = row0 + rg * 16;
        int ar = r0 + l15; if (ar > M - 1) ar = M - 1;
        short8 ahi[4], alo[4];
        #pragma unroll
        for (int kb = 0; kb < 4; kb++) {
            const float4* ap = reinterpret_cast<const float4*>(A + (size_t)ar * D + kb * 32 + quad * 8);
            float4 v0 = ap[0], v1 = ap[1];
            float vv[8] = {v0.x, v0.y, v0.z, v0.w, v1.x, v1.y, v1.z, v1.w};
            short8 vh, vl;
            #pragma unroll
            for (int j = 0; j < 8; j++) {
                unsigned u = __float_as_uint(vv[j]);
                unsigned short h = (unsigned short)(u >> 16);
                vh[j] = (short)h;
                vl[j] = (short)f2bf(vv[j] - bf2f(h));
            }
            ahi[kb] = vh;
            alo[kb] = vl;
        }
        floatx4 acc0 = {0.f, 0.f, 0.f, 0.f};
        floatx4 acc1 = {0.f, 0.f, 0.f, 0.f};
        #pragma unroll
        for (int kb = 0; kb < 4; kb++) {
            acc0 = __builtin_amdgcn_mfma_f32_16x16x32_bf16(ahi[kb], bhi[0][kb], acc0, 0, 0, 0);
            acc1 = __builtin_amdgcn_mfma_f32_16x16x32_bf16(ahi[kb], bhi[1][kb], acc1, 0, 0, 0);
            acc0 = __builtin_amdgcn_mfma_f32_16x16x32_bf16(ahi[kb], blo[0][kb], acc0, 0, 0, 0);
            acc1 = __builtin_amdgcn_mfma_f32_16x16x32_bf16(ahi[kb], blo[1][kb], acc1, 0, 0, 0);
            acc0 = __builtin_amdgcn_mfma_f32_16x16x32_bf16(alo[kb], bhi[0][kb], acc0, 0, 0, 0);
            acc1 = __builtin_amdgcn_mfma_f32_16x16x32_bf16(alo[kb], bhi[1][kb], acc1, 0, 0, 0);
        }
        #pragma unroll
        for (int r = 0; r < 4; r++) {
            int orow = r0 + quad * 4 + r;
            if (orow < M) {
                C[(size_t)orow * D + n0 + l15]      = f2bf(acc0[r]);
                C[(size_t)orow * D + n0 + 16 + l15] = f2bf(acc1[r]);
            }
        }
    }
}

// Quarter-wave agg, epack-free: 4 nodes/wave, 16 lanes/node, lane owns 8
// features via one uint4 (16B) load per edge. esrc[e] and dinv[s] are
// broadcast loads (16 lanes same addr); dinv gather overlaps the H gather.
__device__ __forceinline__ void agg_qbody(const uint4* __restrict__ H4,
                                          const float* __restrict__ dinv,
                                          const int* __restrict__ row_ptr,
                                          const int* __restrict__ esrc,
                                          const float* __restrict__ bias,
                                          int node, int fl, float* acc) {
    #pragma unroll
    for (int j = 0; j < 8; j++) acc[j] = 0.f;
    int beg = row_ptr[node], end = row_ptr[node + 1];
    int e = beg;
    for (; e + 4 <= end; e += 4) {
        int s0 = esrc[e], s1 = esrc[e + 1], s2 = esrc[e + 2], s3 = esrc[e + 3];
        float c0 = dinv[s0], c1 = dinv[s1], c2 = dinv[s2], c3 = dinv[s3];
        uint4 p0 = H4[(size_t)s0 * 16 + fl];
        uint4 p1 = H4[(size_t)s1 * 16 + fl];
        uint4 p2 = H4[(size_t)s2 * 16 + fl];
        uint4 p3 = H4[(size_t)s3 * 16 + fl];
        acc[0] += c0 * bflo(p0.x) + c1 * bflo(p1.x) + c2 * bflo(p2.x) + c3 * bflo(p3.x);
        acc[1] += c0 * bfhi(p0.x) + c1 * bfhi(p1.x) + c2 * bfhi(p2.x) + c3 * bfhi(p3.x);
        acc[2] += c0 * bflo(p0.y) + c1 * bflo(p1.y) + c2 * bflo(p2.y) + c3 * bflo(p3.y);
        acc[3] += c0 * bfhi(p0.y) + c1 * bfhi(p1.y) + c2 * bfhi(p2.y) + c3 * bfhi(p3.y);
        acc[4] += c0 * bflo(p0.z) + c1 * bflo(p1.z) + c2 * bflo(p2.z) + c3 * bflo(p3.z);
        acc[5] += c0 * bfhi(p0.z) + c1 * bfhi(p1.z) + c2 * bfhi(p2.z) + c3 * bfhi(p3.z);
        acc[6] += c0 * bflo(p0.w) + c1 * bflo(p1.w) + c2 * bflo(p2.w) + c3 * bflo(p3.w);
        acc[7] += c0 * bfhi(p0.w) + c1 * bfhi(p1.w) + c2 * bfhi(p2.w) + c3 * bfhi(p3.w);
    }
    for (; e < end; e++) {
        int s0 = esrc[e];
        float c = dinv[s0];
        uint4 p0 = H4[(size_t)s0 * 16 + fl];
        acc[0] += c * bflo(p0.x); acc[1] += c * bfhi(p0.x);
        acc[2] += c * bflo(p0.y); acc[3] += c * bfhi(p0.y);
        acc[4] += c * bflo(p0.z); acc[5] += c * bfhi(p0.z);
        acc[6] += c * bflo(p0.w); acc[7] += c * bfhi(p0.w);
    }
    float di = dinv[node];
    float dii = di * di;
    uint4 ps = H4[(size_t)node * 16 + fl];
    const float4* b4 = (const float4*)bias;
    float4 bb0 = b4[fl * 2], bb1 = b4[fl * 2 + 1];
    #pragma unroll
    for (int j = 0; j < 8; j++) acc[j] *= di;
    acc[0] += dii * bflo(ps.x) + bb0.x;
    acc[1] += dii * bfhi(ps.x) + bb0.y;
    acc[2] += dii * bflo(ps.y) + bb0.z;
    acc[3] += dii * bfhi(ps.y) + bb0.w;
    acc[4] += dii * bflo(ps.z) + bb1.x;
    acc[5] += dii * bfhi(ps.z) + bb1.y;
    acc[6] += dii * bflo(ps.w) + bb1.z;
    acc[7] += dii * bfhi(ps.w) + bb1.w;
}

// Fused layer-1 agg (+b1, ReLU) with row-local layer-2 GEMM on a 16x128 LDS
// tile (rows padded to 136 shorts: 16B-aligned, <=2-way bank aliasing).
__global__ __launch_bounds__(256) void agg_gemm2_kernel(const unsigned short* __restrict__ H,
                                                        const float* __restrict__ dinv,
                                                        const int* __restrict__ row_ptr,
                                                        const int* __restrict__ esrc,
                                                        const float* __restrict__ bias,
                                                        const unsigned short* __restrict__ whi,
                                                        const unsigned short* __restrict__ wlo,
                                                        unsigned short* __restrict__ C, int N) {
    __shared__ unsigned short Asm[16 * 136];
    int tid = threadIdx.x;
    int node0 = blockIdx.x * 16;
    int r = tid >> 4;           // local row 0..15
    int fl = tid & 15;
    int node = node0 + r;
    float acc[8];
    if (node < N) {
        agg_qbody((const uint4*)H, dinv, row_ptr, esrc, bias, node, fl, acc);
    } else {
        #pragma unroll
        for (int j = 0; j < 8; j++) acc[j] = 0.f;
    }
    short8 a;
    #pragma unroll
    for (int j = 0; j < 8; j++) a[j] = (short)f2bf(fmaxf(acc[j], 0.f));
    *reinterpret_cast<short8*>(&Asm[r * 136 + fl * 8]) = a;
    __syncthreads();

    // ---- layer-2 GEMM on the 16-row LDS tile
    int lane = tid & 63, wid = tid >> 6;
    int quad = lane >> 4, l15 = lane & 15;
    int n0 = wid * 32;
    floatx4 acc0 = {0.f, 0.f, 0.f, 0.f};
    floatx4 acc1 = {0.f, 0.f, 0.f, 0.f};
    #pragma unroll 1
    for (int kb = 0; kb < 4; kb++) {
        size_t wb = ((size_t)((kb * 4 + quad) * 128 + (n0 + l15))) * 8;
        short8 bh0 = *reinterpret_cast<const short8*>(whi + wb);
        short8 bh1 = *reinterpret_cast<const short8*>(whi + wb + 128);
        short8 bl0 = *reinterpret_cast<const short8*>(wlo + wb);
        short8 bl1 = *reinterpret_cast<const short8*>(wlo + wb + 128);
        short8 af = *reinterpret_cast<const short8*>(&Asm[l15 * 136 + kb * 32 + quad * 8]);
        acc0 = __builtin_amdgcn_mfma_f32_16x16x32_bf16(af, bh0, acc0, 0, 0, 0);
        acc1 = __builtin_amdgcn_mfma_f32_16x16x32_bf16(af, bh1, acc1, 0, 0, 0);
        acc0 = __builtin_amdgcn_mfma_f32_16x16x32_bf16(af, bl0, acc0, 0, 0, 0);
        acc1 = __builtin_amdgcn_mfma_f32_16x16x32_bf16(af, bl1, acc1, 0, 0, 0);
    }
    #pragma unroll
    for (int rr = 0; rr < 4; rr++) {
        int orow = node0 + quad * 4 + rr;
        if (orow < N) {
            C[(size_t)orow * D + n0 + l15]      = f2bf(acc0[rr]);
            C[(size_t)orow * D + n0 + 16 + l15] = f2bf(acc1[rr]);
        }
    }
}

// Layer-2 agg: fp32 float4 x2 output to d_out.
__global__ __launch_bounds__(256) void agg_f32out_kernel(const unsigned short* __restrict__ H,
                                                         const float* __restrict__ dinv,
                                                         const int* __restrict__ row_ptr,
                                                         const int* __restrict__ esrc,
                                                         const float* __restrict__ bias,
                                                         float4* __restrict__ out, int N) {
    int node = blockIdx.x * 16 + (threadIdx.x >> 4);
    int fl = threadIdx.x & 15;
    if (node >= N) return;
    float acc[8];
    agg_qbody((const uint4*)H, dinv, row_ptr, esrc, bias, node, fl, acc);
    float4 o0, o1;
    o0.x = acc[0]; o0.y = acc[1]; o0.z = acc[2]; o0.w = acc[3];
    o1.x = acc[4]; o1.y = acc[5]; o1.z = acc[6]; o1.w = acc[7];
    out[(size_t)node * 32 + fl * 2]     = o0;
    out[(size_t)node * 32 + fl * 2 + 1] = o1;
}

extern "C" void kernel_launch(void* const* d_in, const int* in_sizes, int n_in,
                              void* d_out, int out_size, void* d_ws, size_t ws_size,
                              hipStream_t stream) {
    const float* x  = (const float*)d_in[0];
    const int*   ei = (const int*)d_in[1];
    const float* W1 = (const float*)d_in[2];
    const float* b1 = (const float*)d_in[3];
    const float* W2 = (const float*)d_in[4];
    const float* b2 = (const float*)d_in[5];

    int N = in_sizes[0] / D;       // 50000 (pack requires N <= 65536)
    int E = in_sizes[1] / 2;       // 600000
    const int* src = ei;
    const int* dst = ei + E;

    int nbuk = (N + 255) / 256;    // 196 buckets

    char* ws = (char*)d_ws;
    int*      bcnt   = (int*)(ws + 0);                    // nbuk*8 ctrs, line-padded (100 KB)
    unsigned* bucket = (unsigned*)(ws + 102400);          // nbuk*8*BCAP*4 = 12.85 MB
    int*      row_ptr= (int*)(ws + 12947456);             // N+1 ints
    float*    dinv   = (float*)(ws + 13147520);           // N floats
    int*      esrcs  = (int*)(ws + 13347520);             // E ints (sorted by dst)
    unsigned short* whi1 = (unsigned short*)(ws + 15747584);
    unsigned short* wlo1 = (unsigned short*)(ws + 15780352);
    unsigned short* whi2 = (unsigned short*)(ws + 15813120);
    unsigned short* wlo2 = (unsigned short*)(ws + 15845888);
    unsigned short* hfeat = (unsigned short*)(ws + 15878656); // N*D bf16 (12.8 MB) : h1 = x@W1
    unsigned short* h2    = (unsigned short*)(ws + 28678656); // N*D bf16 (12.8 MB) : relu(agg1)@W2

    int gb   = (N + 63) / 64;         // gemm blocks (782)
    int ab16 = (N + 15) / 16;         // agg blocks (16 nodes/block)

    hipMemsetAsync(bcnt, 0, 102400, stream);
    bucket_wconv_kernel<<<NBIN + 128, 256, 0, stream>>>(src, dst, bcnt, bucket, E,
                                                        W1, W2, whi1, wlo1, whi2, wlo2, nbuk);

    // CSR build + layer-1 GEMM fused (independent chains)
    build_gemm_kernel<<<nbuk + gb, 256, 0, stream>>>(bucket, bcnt, row_ptr, dinv, esrcs,
                                                     N, E, x, whi1, wlo1, hfeat, N, nbuk);

    // layer 1 agg + b1 + relu fused with layer-2 GEMM -> h2 (bf16)
    agg_gemm2_kernel<<<ab16, 256, 0, stream>>>(hfeat, dinv, row_ptr, esrcs, b1,
                                               whi2, wlo2, h2, N);

    // layer 2 agg + b2 -> d_out (fp32)
    agg_f32out_kernel<<<ab16, 256, 0, stream>>>(h2, dinv, row_ptr, esrcs, b2,
                                                (float4*)d_out, N);
}